// Round 1
// baseline (4258.763 us; speedup 1.0000x reference)
//
#include <hip/hip_runtime.h>

// Problem constants (reference: B,C_IN,C_OUT,K,H,W,NUM = 32,256,256,3,28,28,8)
#define BB    32
#define CIN   256
#define COUT  256
#define KS    3
#define HH    28
#define WW    28
#define NUM   8
#define CCH   8            // channels staged per LDS chunk
#define HP    (HH + 2)     // 30, zero-padded
#define WP    (WW + 2)     // 30
#define NPIX  (HH * WW)    // 784

// One block per (b, o). 256 threads.
//  - w_sh[2304]: this (b,o)'s generated 3x3x256 filter (from weight bank . se[b])
//  - x_sh[8][30][30]: zero-padded input channel chunk
// Each thread owns pixels p = tid, tid+256, tid+512 (always valid since 3*256=768<=784);
// the 16 leftover pixels (768..783) are handled by tid<16 in a separate pass so the
// main tap loop is unconditional.
__global__ __launch_bounds__(256) void dcconv_kernel(
    const float* __restrict__ x,       // [B, CIN, H, W]
    const float* __restrict__ se,      // [B, NUM]
    const float* __restrict__ weight,  // [COUT*CIN*9, NUM]
    const float* __restrict__ bias,    // [COUT]
    float* __restrict__ out)           // [B, COUT, H, W]
{
    const int tid = threadIdx.x;
    const int o   = blockIdx.x & (COUT - 1);
    const int b   = blockIdx.x >> 8;

    __shared__ float w_sh[CIN * KS * KS];     // 9216 B
    __shared__ float x_sh[CCH][HP][WP];       // 28800 B

    // se[b] is block-uniform -> scalar loads
    float se_r[NUM];
#pragma unroll
    for (int n = 0; n < NUM; ++n) se_r[n] = se[b * NUM + n];

    // Generate this (b,o)'s filter: w_sh[i] = dot(weight[o*2304 + i, :], se[b,:])
    // i indexes (c, kh, kw) exactly as the reference reshape does.
#pragma unroll
    for (int it = 0; it < (CIN * KS * KS) / 256; ++it) {
        const int i = tid + it * 256;
        const float4* wr = (const float4*)(weight + (size_t)(o * CIN * KS * KS + i) * NUM);
        const float4 w0 = wr[0];
        const float4 w1 = wr[1];
        w_sh[i] = w0.x * se_r[0] + w0.y * se_r[1] + w0.z * se_r[2] + w0.w * se_r[3]
                + w1.x * se_r[4] + w1.y * se_r[5] + w1.z * se_r[6] + w1.w * se_r[7];
    }

    // Pixel coordinates for the 3 owned pixels
    int ph[3], pw[3];
#pragma unroll
    for (int j = 0; j < 3; ++j) {
        const int p = tid + j * 256;
        ph[j] = p / WW;
        pw[j] = p % WW;
    }
    float acc0 = 0.f, acc1 = 0.f, acc2 = 0.f, acc3 = 0.f;
    const int p3  = 768 + tid;          // only meaningful for tid < 16
    const int ph3 = p3 / WW;
    const int pw3 = p3 % WW;

    const float* xb = x + (size_t)b * CIN * HH * WW;

    for (int c0 = 0; c0 < CIN; c0 += CCH) {
        __syncthreads();   // also covers w_sh readiness on first iteration
        // Stage CCH channels, zero-padded to 30x30
#pragma unroll
        for (int it = 0; it < (CCH * HP * WP + 255) / 256; ++it) {
            const int i = tid + it * 256;
            if (i < CCH * HP * WP) {
                const int c  = i / (HP * WP);
                const int r  = i % (HP * WP);
                const int hh = r / WP;
                const int ww = r % WP;
                float v = 0.f;
                if (hh >= 1 && hh <= HH && ww >= 1 && ww <= WW)
                    v = xb[(size_t)(c0 + c) * HH * WW + (hh - 1) * WW + (ww - 1)];
                x_sh[c][hh][ww] = v;
            }
        }
        __syncthreads();

        // Main tap loop: 3 owned pixels, unconditional
#pragma unroll 2
        for (int c = 0; c < CCH; ++c) {
            const float* wrow = &w_sh[(c0 + c) * KS * KS];
#pragma unroll
            for (int kh = 0; kh < KS; ++kh) {
#pragma unroll
                for (int kw = 0; kw < KS; ++kw) {
                    const float wv = wrow[kh * KS + kw];
                    acc0 += wv * x_sh[c][ph[0] + kh][pw[0] + kw];
                    acc1 += wv * x_sh[c][ph[1] + kh][pw[1] + kw];
                    acc2 += wv * x_sh[c][ph[2] + kh][pw[2] + kw];
                }
            }
        }

        // Leftover pixels 768..783: only wave 0's low 16 lanes; waves 1-3 skip uniformly
        if (tid < 16) {
#pragma unroll 2
            for (int c = 0; c < CCH; ++c) {
                const float* wrow = &w_sh[(c0 + c) * KS * KS];
#pragma unroll
                for (int kh = 0; kh < KS; ++kh) {
#pragma unroll
                    for (int kw = 0; kw < KS; ++kw) {
                        acc3 += wrow[kh * KS + kw] * x_sh[c][ph3 + kh][pw3 + kw];
                    }
                }
            }
        }
    }

    const float bo = bias[o];
    float* ob = out + ((size_t)b * COUT + o) * HH * WW;
    ob[ph[0] * WW + pw[0]] = acc0 + bo;
    ob[ph[1] * WW + pw[1]] = acc1 + bo;
    ob[ph[2] * WW + pw[2]] = acc2 + bo;
    if (tid < 16) ob[ph3 * WW + pw3] = acc3 + bo;
}

extern "C" void kernel_launch(void* const* d_in, const int* in_sizes, int n_in,
                              void* d_out, int out_size, void* d_ws, size_t ws_size,
                              hipStream_t stream) {
    const float* x      = (const float*)d_in[0];  // [32,256,28,28]
    const float* se     = (const float*)d_in[1];  // [32,8]
    const float* weight = (const float*)d_in[2];  // [589824,8]
    const float* bias   = (const float*)d_in[3];  // [256]
    float* out          = (float*)d_out;          // [32,256,28,28]

    dim3 grid(BB * COUT);
    dim3 block(256);
    dcconv_kernel<<<grid, block, 0, stream>>>(x, se, weight, bias, out);
}

// Round 2
// 331.043 us; speedup vs baseline: 12.8647x; 12.8647x over previous
//
#include <hip/hip_runtime.h>
#include <hip/hip_fp16.h>

#define BB    32
#define CIN   256
#define COUT  256
#define KS    3
#define HH    28
#define WW    28
#define NUM   8
#define NPIX  (HH * WW)          // 784
#define KDIM  (CIN * KS * KS)    // 2304
#define HP    30
#define WP    30

// workspace layout (ushort-backed f16):
//   wgen: [B][COUT][9][CIN]  -> 32*256*9*256 = 18,874,368 elems, 37,748,736 B
//   xpad: [B][30][30][CIN]   ->  7,372,800 elems, 14,745,600 B
#define WGEN_ELEMS ((size_t)BB * COUT * 9 * CIN)
#define XPAD_OFF   (WGEN_ELEMS)            // in ushort elements

typedef _Float16 f16x8 __attribute__((ext_vector_type(8)));
typedef float    f32x4 __attribute__((ext_vector_type(4)));

static __device__ __forceinline__ ushort f2h_bits(float v) {
    __half h = __float2half(v);
    return *reinterpret_cast<ushort*>(&h);
}

// ---------------------------------------------------------------------------
// Kernel 1: per-sample filter generation, K-reordered to [b][o][khw][c] (f16)
// grid = COUT blocks, 256 threads (thread = channel c). Each thread reads its
// 9 weight rows (72 floats, contiguous 288 B) once, then emits for all 32 b.
// ---------------------------------------------------------------------------
__global__ __launch_bounds__(256) void gen_w(const float* __restrict__ weight,
                                             const float* __restrict__ se,
                                             ushort* __restrict__ wgen) {
    const int o = blockIdx.x;
    const int c = threadIdx.x;

    __shared__ float se_sh[BB * NUM];   // 256 floats
    se_sh[threadIdx.x] = se[threadIdx.x];

    float4 wr[18];
    const float4* wp = (const float4*)(weight + (size_t)(o * CIN + c) * (KS * KS) * NUM);
#pragma unroll
    for (int i = 0; i < 18; ++i) wr[i] = wp[i];
    __syncthreads();

    for (int b = 0; b < BB; ++b) {
        const float s0 = se_sh[b * 8 + 0], s1 = se_sh[b * 8 + 1];
        const float s2 = se_sh[b * 8 + 2], s3 = se_sh[b * 8 + 3];
        const float s4 = se_sh[b * 8 + 4], s5 = se_sh[b * 8 + 5];
        const float s6 = se_sh[b * 8 + 6], s7 = se_sh[b * 8 + 7];
        ushort* dst = wgen + (((size_t)b * COUT + o) * 9) * CIN + c;
#pragma unroll
        for (int khw = 0; khw < 9; ++khw) {
            const float4 w0 = wr[khw * 2 + 0];
            const float4 w1 = wr[khw * 2 + 1];
            const float v = w0.x * s0 + w0.y * s1 + w0.z * s2 + w0.w * s3
                          + w1.x * s4 + w1.y * s5 + w1.z * s6 + w1.w * s7;
            dst[(size_t)khw * CIN] = f2h_bits(v);
        }
    }
}

// ---------------------------------------------------------------------------
// Kernel 2: x (NCHW fp32) -> zero-padded NHWC f16 [b][30][30][256]
// grid = B*30 blocks (b, hp), 256 threads. Interior rows transpose via LDS
// ([c][w] with +1 pad -> conflict-free both phases).
// ---------------------------------------------------------------------------
__global__ __launch_bounds__(256) void gen_x(const float* __restrict__ x,
                                             ushort* __restrict__ xpad) {
    const int bid = blockIdx.x;
    const int hp  = bid % HP;
    const int b   = bid / HP;
    const int tid = threadIdx.x;

    ushort* row = xpad + ((size_t)b * HP + hp) * WP * CIN;

    if (hp == 0 || hp == HP - 1) {
        uint* r32 = (uint*)row;             // 30*256 ushorts = 3840 uints
        for (int i = tid; i < (WP * CIN) / 2; i += 256) r32[i] = 0u;
        return;
    }

    // zero border columns wp=0 and wp=29 (128 uints each)
    {
        uint* c0 = (uint*)row;
        uint* c1 = (uint*)(row + (WP - 1) * CIN);
        if (tid < 128)       c0[tid] = 0u;
        else                 c1[tid - 128] = 0u;
    }

    __shared__ float lds[CIN * (WW + 1)];   // [c][w], stride 29 -> conflict-free
    const int h = hp - 1;
    const float* xr = x + (size_t)b * CIN * NPIX + h * WW;

    for (int f = tid; f < CIN * WW; f += 256) {
        const int c = f / WW;
        const int w = f % WW;
        lds[c * (WW + 1) + w] = xr[(size_t)c * NPIX + w];
    }
    __syncthreads();

    for (int g = tid; g < WW * CIN; g += 256) {
        const int w = g >> 8;               // 0..27
        const int c = g & 255;
        row[(w + 1) * CIN + c] = f2h_bits(lds[c * (WW + 1) + w]);
    }
}

// ---------------------------------------------------------------------------
// Kernel 3: implicit-GEMM conv via MFMA f32_16x16x32_f16.
// Per sample: D[o, p] = sum_k Wgen[o, k] * im2col[k, p],  M=256, N=784, K=2304.
// Block = 256 threads = 2x2 waves; wave tile 64(M) x 32(N) = 4x2 fragments.
// grid = B * 2(mt) * 13(nt).  K order: khw outer (9), c inner (8 steps of 32).
// A-frag: lane holds Wgen[mo+sub*16+(lane&15)][k0 + (lane>>4)*8 .. +8)] (16 B).
// B-frag: lane holds xpad[b][ph+kh][pw+kw][c0 + (lane>>4)*8 .. +8)]     (16 B).
// Ragged N edge: pixel index clamped for loads, masked for stores.
// ---------------------------------------------------------------------------
__global__ __launch_bounds__(256) void dconv_mfma(const ushort* __restrict__ wgen,
                                                  const ushort* __restrict__ xpad,
                                                  const float* __restrict__ bias,
                                                  float* __restrict__ out) {
    const int bid = blockIdx.x;
    const int nt  = bid % 13;
    const int t2  = bid / 13;
    const int mt  = t2 & 1;
    const int b   = t2 >> 1;

    const int tid  = threadIdx.x;
    const int lane = tid & 63;
    const int wave = tid >> 6;
    const int wm   = wave >> 1;
    const int wn   = wave & 1;
    const int mo   = mt * 128 + wm * 64;
    const int no   = nt * 64 + wn * 32;
    const int col  = lane & 15;
    const int quad = lane >> 4;

    // A pointers (advance 32 elems per K-step, linear across whole loop)
    const ushort* aptr = wgen + ((size_t)b * COUT + (mo + col)) * KDIM + quad * 8;

    // B pixel coords (clamped)
    const int p0  = no + col;
    const int p1  = p0 + 16;
    const int pc0 = p0 > (NPIX - 1) ? (NPIX - 1) : p0;
    const int pc1 = p1 > (NPIX - 1) ? (NPIX - 1) : p1;
    const int ph0 = pc0 / WW, pw0 = pc0 % WW;
    const int ph1 = pc1 / WW, pw1 = pc1 % WW;
    const ushort* xpb = xpad + (size_t)b * HP * WP * CIN + quad * 8;

    f32x4 acc[4][2];
#pragma unroll
    for (int s = 0; s < 4; ++s)
#pragma unroll
        for (int j = 0; j < 2; ++j)
            acc[s][j] = (f32x4){0.f, 0.f, 0.f, 0.f};

    const ushort* ap = aptr;
#pragma unroll
    for (int kh = 0; kh < KS; ++kh) {
#pragma unroll
        for (int kw = 0; kw < KS; ++kw) {
            const ushort* b0 = xpb + (size_t)((ph0 + kh) * WP + (pw0 + kw)) * CIN;
            const ushort* b1 = xpb + (size_t)((ph1 + kh) * WP + (pw1 + kw)) * CIN;
#pragma unroll
            for (int c8 = 0; c8 < 8; ++c8) {
                const f16x8 a0 = *(const f16x8*)(ap);
                const f16x8 a1 = *(const f16x8*)(ap + 16 * KDIM);
                const f16x8 a2 = *(const f16x8*)(ap + 32 * KDIM);
                const f16x8 a3 = *(const f16x8*)(ap + 48 * KDIM);
                const f16x8 f0 = *(const f16x8*)(b0);
                const f16x8 f1 = *(const f16x8*)(b1);
                acc[0][0] = __builtin_amdgcn_mfma_f32_16x16x32_f16(a0, f0, acc[0][0], 0, 0, 0);
                acc[1][0] = __builtin_amdgcn_mfma_f32_16x16x32_f16(a1, f0, acc[1][0], 0, 0, 0);
                acc[2][0] = __builtin_amdgcn_mfma_f32_16x16x32_f16(a2, f0, acc[2][0], 0, 0, 0);
                acc[3][0] = __builtin_amdgcn_mfma_f32_16x16x32_f16(a3, f0, acc[3][0], 0, 0, 0);
                acc[0][1] = __builtin_amdgcn_mfma_f32_16x16x32_f16(a0, f1, acc[0][1], 0, 0, 0);
                acc[1][1] = __builtin_amdgcn_mfma_f32_16x16x32_f16(a1, f1, acc[1][1], 0, 0, 0);
                acc[2][1] = __builtin_amdgcn_mfma_f32_16x16x32_f16(a2, f1, acc[2][1], 0, 0, 0);
                acc[3][1] = __builtin_amdgcn_mfma_f32_16x16x32_f16(a3, f1, acc[3][1], 0, 0, 0);
                ap += 32;
                b0 += 32;
                b1 += 32;
            }
        }
    }

    // Epilogue: D row = quad*4 + r, col = lane&15 (verified m89/m91 layout)
    float* ob = out + (size_t)b * COUT * NPIX;
#pragma unroll
    for (int s = 0; s < 4; ++s) {
        const int m = mo + s * 16 + quad * 4;
#pragma unroll
        for (int j = 0; j < 2; ++j) {
            const int p = no + j * 16 + col;
            if (p < NPIX) {
#pragma unroll
                for (int r = 0; r < 4; ++r) {
                    ob[(size_t)(m + r) * NPIX + p] = acc[s][j][r] + bias[m + r];
                }
            }
        }
    }
}

extern "C" void kernel_launch(void* const* d_in, const int* in_sizes, int n_in,
                              void* d_out, int out_size, void* d_ws, size_t ws_size,
                              hipStream_t stream) {
    const float* x      = (const float*)d_in[0];  // [32,256,28,28]
    const float* se     = (const float*)d_in[1];  // [32,8]
    const float* weight = (const float*)d_in[2];  // [589824,8]
    const float* bias   = (const float*)d_in[3];  // [256]
    float* out          = (float*)d_out;          // [32,256,28,28]

    ushort* wgen = (ushort*)d_ws;
    ushort* xpad = (ushort*)d_ws + XPAD_OFF;
    (void)ws_size; (void)in_sizes; (void)n_in; (void)out_size;

    gen_w<<<dim3(COUT), dim3(256), 0, stream>>>(weight, se, wgen);
    gen_x<<<dim3(BB * HP), dim3(256), 0, stream>>>(x, xpad);
    dconv_mfma<<<dim3(BB * 2 * 13), dim3(256), 0, stream>>>(wgen, xpad, bias, out);
}

// Round 3
// 162.756 us; speedup vs baseline: 26.1665x; 2.0340x over previous
//
#include <hip/hip_runtime.h>
#include <hip/hip_fp16.h>

#define BB    32
#define CIN   256
#define COUT  256
#define HH    28
#define WW    28
#define NPIX  784
#define KD    2304            // 9 * 256
#define HP    30
#define WP    30

#define BM    128
#define BN    128
#define NT    7               // ceil(784/128)

// workspace: wgen [b][o][khw][c] f16 (18.87M elems), xpad [b][30][30][256] f16
#define WGEN_ELEMS ((size_t)BB * COUT * KD)
#define XPAD_OFF   (WGEN_ELEMS)

typedef _Float16 f16x8 __attribute__((ext_vector_type(8)));
typedef float    f32x4 __attribute__((ext_vector_type(4)));

static __device__ __forceinline__ ushort f2h_bits(float v) {
    __half h = __float2half(v);
    return *reinterpret_cast<ushort*>(&h);
}

static __device__ __forceinline__ void gll16(const ushort* g, ushort* l) {
    __builtin_amdgcn_global_load_lds(
        (const __attribute__((address_space(1))) unsigned int*)g,
        (__attribute__((address_space(3))) unsigned int*)l, 16, 0, 0);
}

// ---------------------------------------------------------------------------
// Kernel 1: filter generation -> wgen[b][o][khw][c] (f16), coalesced stores.
// Block = o (256 blocks), thread = c. Per b: compute 9 taps -> LDS repack ->
// 16B vector stores.
// ---------------------------------------------------------------------------
__global__ __launch_bounds__(256) void gen_w(const float* __restrict__ weight,
                                             const float* __restrict__ se,
                                             ushort* __restrict__ wgen) {
    const int o = blockIdx.x;
    const int c = threadIdx.x;

    __shared__ float  se_sh[BB * 8];
    __shared__ ushort w_sh[KD];          // 4608 B

    se_sh[c] = se[c];

    float4 wr[18];
    const float4* wp = (const float4*)(weight + (size_t)(o * CIN + c) * 9 * 8);
#pragma unroll
    for (int i = 0; i < 18; ++i) wr[i] = wp[i];
    __syncthreads();

    for (int b = 0; b < BB; ++b) {
        const float s0 = se_sh[b * 8 + 0], s1 = se_sh[b * 8 + 1];
        const float s2 = se_sh[b * 8 + 2], s3 = se_sh[b * 8 + 3];
        const float s4 = se_sh[b * 8 + 4], s5 = se_sh[b * 8 + 5];
        const float s6 = se_sh[b * 8 + 6], s7 = se_sh[b * 8 + 7];
#pragma unroll
        for (int khw = 0; khw < 9; ++khw) {
            const float4 w0 = wr[khw * 2 + 0];
            const float4 w1 = wr[khw * 2 + 1];
            const float v = w0.x * s0 + w0.y * s1 + w0.z * s2 + w0.w * s3
                          + w1.x * s4 + w1.y * s5 + w1.z * s6 + w1.w * s7;
            w_sh[khw * 256 + c] = f2h_bits(v);
        }
        __syncthreads();
        // 2304 ushorts = 288 x 16B chunks, coalesced
        const uint4* src = (const uint4*)w_sh;
        uint4* dst = (uint4*)(wgen + ((size_t)b * COUT + o) * KD);
        dst[c] = src[c];
        if (c < 32) dst[256 + c] = src[256 + c];
        __syncthreads();
    }
}

// ---------------------------------------------------------------------------
// Kernel 2: x (NCHW fp32) -> zero-padded NHWC f16 [b][30][30][256]
// ---------------------------------------------------------------------------
__global__ __launch_bounds__(256) void gen_x(const float* __restrict__ x,
                                             ushort* __restrict__ xpad) {
    const int bid = blockIdx.x;
    const int hp  = bid % HP;
    const int b   = bid / HP;
    const int tid = threadIdx.x;

    ushort* row = xpad + ((size_t)b * HP + hp) * WP * CIN;

    if (hp == 0 || hp == HP - 1) {
        uint* r32 = (uint*)row;
        for (int i = tid; i < (WP * CIN) / 2; i += 256) r32[i] = 0u;
        return;
    }
    {
        uint* c0 = (uint*)row;
        uint* c1 = (uint*)(row + (WP - 1) * CIN);
        if (tid < 128)       c0[tid] = 0u;
        else                 c1[tid - 128] = 0u;
    }

    __shared__ float lds[CIN * (WW + 1)];
    const int h = hp - 1;
    const float* xr = x + (size_t)b * CIN * NPIX + h * WW;

    for (int f = tid; f < CIN * WW; f += 256) {
        const int c = f / WW;
        const int w = f % WW;
        lds[c * (WW + 1) + w] = xr[(size_t)c * NPIX + w];
    }
    __syncthreads();
    for (int g = tid; g < WW * CIN; g += 256) {
        const int w = g >> 8;
        const int c = g & 255;
        row[(w + 1) * CIN + c] = f2h_bits(lds[c * (WW + 1) + w]);
    }
}

// ---------------------------------------------------------------------------
// Kernel 3: implicit-GEMM conv, LDS-staged, shifted-window B.
// Per sample: M=256(o), N=784(p), K=2304. Block: BM=128 x BN=128 pixels.
// K-loop: c32-chunk outer (8; stages the 8x30 xpad patch once), khw inner (9).
// A-tile (128x32 f16 = 8 KB) restaged per K-step via global_load_lds w/ XOR
// chunk swizzle (2-way bank aliasing = free). Patch layout [quad][8][30][8f16]
// -> stride-1 chunk reads, conflict-free.
// ---------------------------------------------------------------------------
__global__ __launch_bounds__(256) void dconv_mfma(const ushort* __restrict__ wgen,
                                                  const ushort* __restrict__ xpad,
                                                  const float* __restrict__ bias,
                                                  float* __restrict__ out) {
    // XCD-grouping remap: 448 = 8 * 56; 56 = 8 slices x 7 nt per XCD.
    const int bid   = blockIdx.x;
    const int g     = bid & 7;
    const int s     = bid >> 3;            // 0..55
    const int nt    = s % NT;
    const int slice = g + 8 * (s / NT);    // 0..63 = b*2 + mt
    const int b     = slice >> 1;
    const int mt    = slice & 1;

    const int tid  = threadIdx.x;
    const int lane = tid & 63;
    const int wave = tid >> 6;
    const int wm   = wave >> 1;
    const int wn   = wave & 1;
    const int col  = lane & 15;
    const int quad = lane >> 4;

    __shared__ ushort Ash[BM * 32];        // 8192 B, swizzled 16B chunks
    __shared__ ushort Psh[4 * 8 * 30 * 8]; // 15360 B: [quad][row][w][8 f16]

    const int mo   = mt * BM + wm * 64;
    const int no   = nt * BN + wn * 64;
    const int h_lo = (nt * BN) / WW;       // lowest xpad row touched

    // B per-lane pixel bases (chunk index within a quad-plane), clamped
    int  pixbase[4];
    int  pst[4];
#pragma unroll
    for (int j = 0; j < 4; ++j) {
        const int p  = no + j * 16 + col;
        pst[j] = p;
        const int pc = p > (NPIX - 1) ? (NPIX - 1) : p;
        const int h  = pc / WW;
        const int w  = pc % WW;
        pixbase[j] = (h - h_lo) * 30 + w;
    }

    // A frag chunk base: chunkpos(m, quad) = m*4 + (quad ^ ((m>>1)&3))
    const int s_sw  = (col >> 1) & 3;
    const int abase = ((wm * 64 + col) << 2) + (quad ^ s_sw);   // + sub*64 chunks

    const ushort* wg = wgen + ((size_t)b * COUT + mt * BM) * KD;
    const ushort* xp = xpad + (size_t)b * HP * WP * CIN;

    f32x4 acc[4][4];
#pragma unroll
    for (int mi = 0; mi < 4; ++mi)
#pragma unroll
        for (int nj = 0; nj < 4; ++nj)
            acc[mi][nj] = (f32x4){0.f, 0.f, 0.f, 0.f};

    for (int c32 = 0; c32 < 8; ++c32) {
        __syncthreads();   // all waves done reading Ash/Psh from prev step

        // ---- stage patch for this c32: 960 chunks of 16B ----
#pragma unroll
        for (int r = 0; r < 4; ++r) {
            const int j = r * 256 + tid;
            if (j < 960) {                       // round 3: waves 0-2 only
                const int qc  = j / 240;
                const int rem = j % 240;
                const int rr  = rem / 30;
                const int ww  = rem % 30;
                int srow = h_lo + rr;
                if (srow > 29) srow = 29;
                gll16(xp + ((size_t)srow * WP + ww) * CIN + c32 * 32 + qc * 8,
                      Psh + (size_t)j * 8);
            }
        }
        // ---- stage A for khw = 0 ----
#pragma unroll
        for (int r = 0; r < 2; ++r) {
            const int cch = r * 256 + tid;       // 0..511
            const int m   = cch >> 2;
            const int kc  = (cch & 3) ^ ((m >> 1) & 3);
            gll16(wg + ((size_t)m * 9 + 0) * CIN + c32 * 32 + kc * 8,
                  Ash + (size_t)cch * 8);
        }

#pragma unroll
        for (int khw = 0; khw < 9; ++khw) {
            if (khw > 0) {
                __syncthreads();                 // done reading prev A-tile
#pragma unroll
                for (int r = 0; r < 2; ++r) {
                    const int cch = r * 256 + tid;
                    const int m   = cch >> 2;
                    const int kc  = (cch & 3) ^ ((m >> 1) & 3);
                    gll16(wg + ((size_t)m * 9 + khw) * CIN + c32 * 32 + kc * 8,
                          Ash + (size_t)cch * 8);
                }
            }
            __syncthreads();                     // staging visible

            const int koff = (khw / 3) * 30 + (khw % 3);

            f16x8 af[4];
#pragma unroll
            for (int sub = 0; sub < 4; ++sub)
                af[sub] = ((const f16x8*)Ash)[abase + sub * 64];

            f16x8 bf[4];
#pragma unroll
            for (int j = 0; j < 4; ++j)
                bf[j] = ((const f16x8*)Psh)[quad * 240 + pixbase[j] + koff];

#pragma unroll
            for (int mi = 0; mi < 4; ++mi)
#pragma unroll
                for (int nj = 0; nj < 4; ++nj)
                    acc[mi][nj] = __builtin_amdgcn_mfma_f32_16x16x32_f16(
                        af[mi], bf[nj], acc[mi][nj], 0, 0, 0);
        }
    }

    // ---- epilogue ----
    float* ob = out + (size_t)b * COUT * NPIX;
#pragma unroll
    for (int mi = 0; mi < 4; ++mi) {
        const int m = mo + mi * 16 + quad * 4;
        const float4 bv = *(const float4*)(bias + m);
#pragma unroll
        for (int nj = 0; nj < 4; ++nj) {
            const int p = pst[nj];
            if (p < NPIX) {
                ob[(size_t)(m + 0) * NPIX + p] = acc[mi][nj][0] + bv.x;
                ob[(size_t)(m + 1) * NPIX + p] = acc[mi][nj][1] + bv.y;
                ob[(size_t)(m + 2) * NPIX + p] = acc[mi][nj][2] + bv.z;
                ob[(size_t)(m + 3) * NPIX + p] = acc[mi][nj][3] + bv.w;
            }
        }
    }
}

extern "C" void kernel_launch(void* const* d_in, const int* in_sizes, int n_in,
                              void* d_out, int out_size, void* d_ws, size_t ws_size,
                              hipStream_t stream) {
    const float* x      = (const float*)d_in[0];
    const float* se     = (const float*)d_in[1];
    const float* weight = (const float*)d_in[2];
    const float* bias   = (const float*)d_in[3];
    float* out          = (float*)d_out;

    ushort* wgen = (ushort*)d_ws;
    ushort* xpad = (ushort*)d_ws + XPAD_OFF;
    (void)ws_size; (void)in_sizes; (void)n_in; (void)out_size;

    gen_w<<<dim3(COUT), dim3(256), 0, stream>>>(weight, se, wgen);
    gen_x<<<dim3(BB * HP), dim3(256), 0, stream>>>(x, xpad);
    dconv_mfma<<<dim3(BB * 2 * NT), dim3(256), 0, stream>>>(wgen, xpad, bias, out);
}

// Round 4
// 162.732 us; speedup vs baseline: 26.1704x; 1.0001x over previous
//
#include <hip/hip_runtime.h>
#include <hip/hip_fp16.h>

#define BB    32
#define CIN   256
#define COUT  256
#define HH    28
#define WW    28
#define NPIX  784
#define KD    2304            // 9 * 256
#define HP    30
#define WP    30

#define BM    128
#define BN    128
#define NT    7               // ceil(784/128)

// workspace: wgen [b][o][khw][c] f16 (18.87M elems), xpad [b][30][30][256] f16
#define WGEN_ELEMS ((size_t)BB * COUT * KD)
#define XPAD_OFF   (WGEN_ELEMS)

typedef _Float16 f16x8 __attribute__((ext_vector_type(8)));
typedef float    f32x4 __attribute__((ext_vector_type(4)));

static __device__ __forceinline__ ushort f2h_bits(float v) {
    __half h = __float2half(v);
    return *reinterpret_cast<ushort*>(&h);
}

static __device__ __forceinline__ void gll16(const ushort* g, ushort* l) {
    __builtin_amdgcn_global_load_lds(
        (const __attribute__((address_space(1))) unsigned int*)g,
        (__attribute__((address_space(3))) unsigned int*)l, 16, 0, 0);
}

// ---------------------------------------------------------------------------
// Kernel 1: filter generation -> wgen[b][o][khw][c] (f16).
// grid = COUT * 8 (8 b-groups of 4 samples). Weight re-read 8x (L3-resident).
// ---------------------------------------------------------------------------
__global__ __launch_bounds__(256) void gen_w(const float* __restrict__ weight,
                                             const float* __restrict__ se,
                                             ushort* __restrict__ wgen) {
    const int o  = blockIdx.x & 255;
    const int bg = blockIdx.x >> 8;      // 0..7
    const int c  = threadIdx.x;

    __shared__ float  se_sh[BB * 8];
    __shared__ ushort w_sh[KD];          // 4608 B

    se_sh[c] = se[c];

    float4 wr[18];
    const float4* wp = (const float4*)(weight + (size_t)(o * CIN + c) * 9 * 8);
#pragma unroll
    for (int i = 0; i < 18; ++i) wr[i] = wp[i];
    __syncthreads();

#pragma unroll
    for (int bi = 0; bi < 4; ++bi) {
        const int b = bg * 4 + bi;
        const float s0 = se_sh[b * 8 + 0], s1 = se_sh[b * 8 + 1];
        const float s2 = se_sh[b * 8 + 2], s3 = se_sh[b * 8 + 3];
        const float s4 = se_sh[b * 8 + 4], s5 = se_sh[b * 8 + 5];
        const float s6 = se_sh[b * 8 + 6], s7 = se_sh[b * 8 + 7];
#pragma unroll
        for (int khw = 0; khw < 9; ++khw) {
            const float4 w0 = wr[khw * 2 + 0];
            const float4 w1 = wr[khw * 2 + 1];
            const float v = w0.x * s0 + w0.y * s1 + w0.z * s2 + w0.w * s3
                          + w1.x * s4 + w1.y * s5 + w1.z * s6 + w1.w * s7;
            w_sh[khw * 256 + c] = f2h_bits(v);
        }
        __syncthreads();
        const uint4* src = (const uint4*)w_sh;
        uint4* dst = (uint4*)(wgen + ((size_t)b * COUT + o) * KD);
        dst[c] = src[c];
        if (c < 32) dst[256 + c] = src[256 + c];
        __syncthreads();
    }
}

// ---------------------------------------------------------------------------
// Kernel 2: x (NCHW fp32) -> zero-padded NHWC f16 [b][30][30][256]
// ---------------------------------------------------------------------------
__global__ __launch_bounds__(256) void gen_x(const float* __restrict__ x,
                                             ushort* __restrict__ xpad) {
    const int bid = blockIdx.x;
    const int hp  = bid % HP;
    const int b   = bid / HP;
    const int tid = threadIdx.x;

    ushort* row = xpad + ((size_t)b * HP + hp) * WP * CIN;

    if (hp == 0 || hp == HP - 1) {
        uint* r32 = (uint*)row;
        for (int i = tid; i < (WP * CIN) / 2; i += 256) r32[i] = 0u;
        return;
    }
    {
        uint* c0 = (uint*)row;
        uint* c1 = (uint*)(row + (WP - 1) * CIN);
        if (tid < 128)       c0[tid] = 0u;
        else                 c1[tid - 128] = 0u;
    }

    __shared__ float lds[CIN * (WW + 1)];
    const int h = hp - 1;
    const float* xr = x + (size_t)b * CIN * NPIX + h * WW;

    for (int f = tid; f < CIN * WW; f += 256) {
        const int c = f / WW;
        const int w = f % WW;
        lds[c * (WW + 1) + w] = xr[(size_t)c * NPIX + w];
    }
    __syncthreads();
    for (int g = tid; g < WW * CIN; g += 256) {
        const int w = g >> 8;
        const int c = g & 255;
        row[(w + 1) * CIN + c] = f2h_bits(lds[c * (WW + 1) + w]);
    }
}

// ---------------------------------------------------------------------------
// Kernel 3: implicit-GEMM conv, single-barrier double-buffered pipeline.
// Per sample: M=256(o), N=784(p), K=2304. Block tile 128x128, wave 64x64.
// 72 K-steps (c32 outer x khw inner). Per step: one __syncthreads (drains the
// prefetch issued last step), issue next step's global_load_lds prefetch into
// the alternate buffer, compute current step (8 ds_read_b128 + 16 MFMA).
// Ash alternates per step; Psh (shifted-window patch) alternates per c32.
// ---------------------------------------------------------------------------
__global__ __launch_bounds__(256) void dconv_mfma(const ushort* __restrict__ wgen,
                                                  const ushort* __restrict__ xpad,
                                                  const float* __restrict__ bias,
                                                  float* __restrict__ out) {
    // XCD-grouping remap: all 7 nt of a (b,mt) slice on one XCD.
    const int bid   = blockIdx.x;
    const int g     = bid & 7;
    const int s     = bid >> 3;            // 0..55
    const int nt    = s % NT;
    const int slice = g + 8 * (s / NT);    // 0..63 = b*2 + mt
    const int b     = slice >> 1;
    const int mt    = slice & 1;

    const int tid  = threadIdx.x;
    const int lane = tid & 63;
    const int wave = tid >> 6;
    const int wm   = wave >> 1;
    const int wn   = wave & 1;
    const int col  = lane & 15;
    const int quad = lane >> 4;

    __shared__ ushort Ash[2][BM * 32];        // 2 x 8192 B
    __shared__ ushort Psh[2][4 * 8 * 30 * 8]; // 2 x 15360 B

    const int mo   = mt * BM + wm * 64;
    const int no   = nt * BN + wn * 64;
    const int h_lo = (nt * BN) / WW;

    const ushort* wg = wgen + ((size_t)b * COUT + mt * BM) * KD;
    const ushort* xp = xpad + (size_t)b * HP * WP * CIN;

    // ---- precomputed staging offsets (hoisted out of the K-loop) ----
    // A: 2 chunks/thread. goff = m*9*CIN + kc*8 (+ khw*256 + c32*32)
    int a_goff[2], a_loff[2];
#pragma unroll
    for (int r = 0; r < 2; ++r) {
        const int cch = r * 256 + tid;
        const int m   = cch >> 2;
        const int kc  = (cch & 3) ^ ((m >> 1) & 3);
        a_goff[r] = m * 9 * CIN + kc * 8;
        a_loff[r] = cch * 8;
    }
    // Patch: up to 4 chunks/thread (960 total). goff = (srow*WP+ww)*CIN + qc*8
    int p_goff[4], p_loff[4];
    bool p_ok[4];
#pragma unroll
    for (int r = 0; r < 4; ++r) {
        const int j = r * 256 + tid;
        p_ok[r] = (j < 960);
        const int jj  = p_ok[r] ? j : 0;
        const int qc  = jj / 240;
        const int rem = jj % 240;
        const int rr  = rem / 30;
        const int ww  = rem % 30;
        int srow = h_lo + rr;
        if (srow > 29) srow = 29;
        p_goff[r] = (srow * WP + ww) * CIN + qc * 8;
        p_loff[r] = jj * 8;
    }

    // B-fragment read positions
    int pixbase[4], pst[4];
#pragma unroll
    for (int j = 0; j < 4; ++j) {
        const int p  = no + j * 16 + col;
        pst[j] = p;
        const int pc = p > (NPIX - 1) ? (NPIX - 1) : p;
        pixbase[j] = (pc / WW - h_lo) * 30 + (pc % WW);
    }
    // A-fragment read base (XOR chunk swizzle)
    const int s_sw  = (col >> 1) & 3;
    const int abase = ((wm * 64 + col) << 2) + (quad ^ s_sw);

    f32x4 acc[4][4];
#pragma unroll
    for (int mi = 0; mi < 4; ++mi)
#pragma unroll
        for (int nj = 0; nj < 4; ++nj)
            acc[mi][nj] = (f32x4){0.f, 0.f, 0.f, 0.f};

    // ---- prologue: stage step 0 (A khw=0,c32=0 -> buf0; patch c32=0 -> buf0)
#pragma unroll
    for (int r = 0; r < 2; ++r)
        gll16(wg + a_goff[r], &Ash[0][a_loff[r]]);
#pragma unroll
    for (int r = 0; r < 4; ++r)
        if (p_ok[r]) gll16(xp + p_goff[r], &Psh[0][p_loff[r]]);

    // ---- main pipeline: 72 steps, one barrier each ----
    for (int step = 0; step < 72; ++step) {
        const int khw  = step % 9;
        const int c32  = step / 9;
        const int abuf = step & 1;
        const int pbuf = c32 & 1;

        __syncthreads();   // drains own vmcnt -> buffers for this step visible;
                           // also: all waves done reading the buffers we're
                           // about to overwrite with the next prefetch.

        if (step + 1 < 72) {
            const int nkhw = (step + 1) % 9;
            const int nc32 = (step + 1) / 9;
            const int aoff = nkhw * 256 + nc32 * 32;
#pragma unroll
            for (int r = 0; r < 2; ++r)
                gll16(wg + a_goff[r] + aoff, &Ash[abuf ^ 1][a_loff[r]]);
            if (nkhw == 0) {
                const int poff = nc32 * 32;
#pragma unroll
                for (int r = 0; r < 4; ++r)
                    if (p_ok[r]) gll16(xp + p_goff[r] + poff,
                                       &Psh[pbuf ^ 1][p_loff[r]]);
            }
        }

        const int koff = (khw / 3) * 30 + (khw % 3);

        f16x8 af[4];
#pragma unroll
        for (int sub = 0; sub < 4; ++sub)
            af[sub] = ((const f16x8*)Ash[abuf])[abase + sub * 64];

        f16x8 bf[4];
#pragma unroll
        for (int j = 0; j < 4; ++j)
            bf[j] = ((const f16x8*)Psh[pbuf])[quad * 240 + pixbase[j] + koff];

#pragma unroll
        for (int mi = 0; mi < 4; ++mi)
#pragma unroll
            for (int nj = 0; nj < 4; ++nj)
                acc[mi][nj] = __builtin_amdgcn_mfma_f32_16x16x32_f16(
                    af[mi], bf[nj], acc[mi][nj], 0, 0, 0);
    }

    // ---- epilogue ----
    float* ob = out + (size_t)b * COUT * NPIX;
#pragma unroll
    for (int mi = 0; mi < 4; ++mi) {
        const int m = mo + mi * 16 + quad * 4;
        const float4 bv = *(const float4*)(bias + m);
#pragma unroll
        for (int nj = 0; nj < 4; ++nj) {
            const int p = pst[nj];
            if (p < NPIX) {
                ob[(size_t)(m + 0) * NPIX + p] = acc[mi][nj][0] + bv.x;
                ob[(size_t)(m + 1) * NPIX + p] = acc[mi][nj][1] + bv.y;
                ob[(size_t)(m + 2) * NPIX + p] = acc[mi][nj][2] + bv.z;
                ob[(size_t)(m + 3) * NPIX + p] = acc[mi][nj][3] + bv.w;
            }
        }
    }
}

extern "C" void kernel_launch(void* const* d_in, const int* in_sizes, int n_in,
                              void* d_out, int out_size, void* d_ws, size_t ws_size,
                              hipStream_t stream) {
    const float* x      = (const float*)d_in[0];
    const float* se     = (const float*)d_in[1];
    const float* weight = (const float*)d_in[2];
    const float* bias   = (const float*)d_in[3];
    float* out          = (float*)d_out;

    ushort* wgen = (ushort*)d_ws;
    ushort* xpad = (ushort*)d_ws + XPAD_OFF;
    (void)ws_size; (void)in_sizes; (void)n_in; (void)out_size;

    gen_w<<<dim3(COUT * 8), dim3(256), 0, stream>>>(weight, se, wgen);
    gen_x<<<dim3(BB * HP), dim3(256), 0, stream>>>(x, xpad);
    dconv_mfma<<<dim3(BB * 2 * NT), dim3(256), 0, stream>>>(wgen, xpad, bias, out);
}